// Round 13
// baseline (4526.439 us; speedup 1.0000x reference)
//
#include <hip/hip_runtime.h>
#include <math.h>

typedef _Float16 f16;
typedef _Float16 f16x8 __attribute__((ext_vector_type(8)));
typedef float f32x16 __attribute__((ext_vector_type(16)));

#define NB 32768
#define NH 512
#define NM 128
#define NIN 640
#define NHID 2048
#define NOUT 642
#define NOUTP 768
#define ITERS 16
// 2-split f16: v = a0 + a1*EPS1,  EPS1=2^-11 (residual scaled by S1 -> stays f16-normal)
#define S1 2048.0f
#define EPS1 4.8828125e-4f

__device__ __forceinline__ void gload16(const void* g, void* lds) {
  __builtin_amdgcn_global_load_lds(
      reinterpret_cast<const __attribute__((address_space(1))) unsigned int*>((uintptr_t)g),
      reinterpret_cast<__attribute__((address_space(3))) unsigned int*>((unsigned int)(uintptr_t)lds),
      16, 0, 0);
}

__device__ __forceinline__ f32x16 mfma32(f16x8 a, f16x8 b, f32x16 c) {
  return __builtin_amdgcn_mfma_f32_32x32x16_f16(a, b, c, 0, 0, 0);
}

__device__ __forceinline__ void split2(float v, f16& a0, f16& a1) {
  a0 = (f16)v;
  a1 = (f16)((v - (float)a0) * S1);
}

// ---------------- weight transpose + 2-split: W[K][Nreal] -> WT[n][2][K] ----------------
__global__ void k_prepW(const float* __restrict__ W, f16* __restrict__ WT,
                        int K, int Nreal) {
  __shared__ float tile[32][33];
  int k0 = blockIdx.x * 32, n0 = blockIdx.y * 32;
  int tx = threadIdx.x & 31, ty = threadIdx.x >> 5;
#pragma unroll
  for (int r = 0; r < 4; ++r) {
    int kk = ty + 8 * r;
    int n = n0 + tx;
    tile[kk][tx] = (n < Nreal) ? W[(size_t)(k0 + kk) * Nreal + n] : 0.0f;
  }
  __syncthreads();
#pragma unroll
  for (int r = 0; r < 4; ++r) {
    int nl = ty + 8 * r;
    float v = tile[tx][nl];
    f16 a0, a1; split2(v, a0, a1);
    size_t o = (size_t)(n0 + nl) * (2 * K) + k0 + tx;
    WT[o] = a0; WT[o + K] = a1;
  }
}

// ---------------- split x into merged state xm2[row][2][640] (x cols 0..511) ----------------
__global__ void k_splitX(const float* __restrict__ x, f16* __restrict__ xm2) {
  int i = blockIdx.x * 256 + threadIdx.x;
  int row = i >> 9, c = i & 511;
  f16 a0, a1; split2(x[i], a0, a1);
  size_t o = (size_t)row * (2 * NIN) + c;
  xm2[o] = a0; xm2[o + NIN] = a1;
}

// ---------------- init mem part of xm2 (cols 512..639), fp/list/cnt ----------------
__global__ void k_init(f16* __restrict__ xm2, float* __restrict__ fpb,
                       int* __restrict__ list0, int* __restrict__ cnt) {
  int gid = blockIdx.x * blockDim.x + threadIdx.x;
  if (gid < NB * NM) {
    int row = gid >> 7, c = gid & 127;
    size_t o = (size_t)row * (2 * NIN) + 512 + c;
    xm2[o] = (f16)((c == 0) ? 16.0f : 0.0f);
    xm2[o + NIN] = (f16)0.0f;
  }
  if (gid < NB) { fpb[gid] = 0.0f; list0[gid] = gid; }
  if (gid < 32) cnt[gid] = (gid == 0) ? NB : 0;
}

// ===== GEMM: 128x128 tile, BK=32, 256 thr = 4 waves (2x2), wave tile 64x64 =====
// MFMA 32x32x16_f16 (2x2 frags/wave, 2 ksub, 3 passes = 24 MFMA/wave/K-step).
// LDS per buffer: A planes 128x32 @ {0,4096}, B planes @ {8192,12288} f16; dbuf 64 KB -> 2 blk/CU.
// k-slot swizzle FIXED (r12 had 4-way conflicts, 1.7e7/dispatch):
//   xor(row) = ((row>>1)&3) ^ ((row>>3)&3)   <- second term decorrelates 8-row stripes
// Enumeration: per ds_read_b128, each 16B slot gets exactly 8 lanes -> 8 dword-acc/bank
// (balanced minimum). Staged via pre-swizzled global source (same xor; invariant to row+64).
// C/D layout (m74/m101): col=lane&31, row=(reg&3)+8*(reg>>2)+4*(lane>>5).

#define GEMM_PREAMBLE()                                                     \
  int tid = threadIdx.x;                                                    \
  int w = tid >> 6, lane = tid & 63;                                        \
  int wr = w >> 1, wc = w & 1;                                              \
  int l31 = lane & 31, kg = lane >> 5;                                      \
  int ksrc = (((tid & 3) ^ ((tid >> 3) & 3) ^ ((tid >> 5) & 3)) << 3);      \
  int stg = tid * 8;                                                        \
  int afo[2][2], bfo[2][2];                                                 \
  _Pragma("unroll") for (int mi = 0; mi < 2; ++mi)                          \
  _Pragma("unroll") for (int ks = 0; ks < 2; ++ks) {                        \
    int row = wr * 64 + mi * 32 + l31;                                      \
    int xr = ((row >> 1) & 3) ^ ((row >> 3) & 3);                           \
    afo[mi][ks] = row * 32 + ((((ks << 1) + kg) ^ xr) << 3);                \
  }                                                                         \
  _Pragma("unroll") for (int ni = 0; ni < 2; ++ni)                          \
  _Pragma("unroll") for (int ks = 0; ks < 2; ++ks) {                        \
    int row = wc * 64 + ni * 32 + l31;                                      \
    int xr = ((row >> 1) & 3) ^ ((row >> 3) & 3);                           \
    bfo[ni][ks] = 8192 + row * 32 + ((((ks << 1) + kg) ^ xr) << 3);         \
  }                                                                         \
  f32x16 acc0[2][2], acc1[2][2];                                            \
  _Pragma("unroll") for (int mi = 0; mi < 2; ++mi)                          \
  _Pragma("unroll") for (int ni = 0; ni < 2; ++ni) {                        \
    acc0[mi][ni] = (f32x16)0.0f; acc1[mi][ni] = (f32x16)0.0f;               \
  }

#define GEMM_COMPUTE(BASE)                                                  \
  {                                                                         \
    const f16* _sb = (BASE);                                                \
    _Pragma("unroll") for (int ks = 0; ks < 2; ++ks) {                      \
      f16x8 fa0[2], fa1[2], fb0[2], fb1[2];                                 \
      _Pragma("unroll") for (int mi = 0; mi < 2; ++mi) {                    \
        fa0[mi] = *(const f16x8*)&_sb[afo[mi][ks]];                         \
        fa1[mi] = *(const f16x8*)&_sb[4096 + afo[mi][ks]];                  \
      }                                                                     \
      _Pragma("unroll") for (int ni = 0; ni < 2; ++ni) {                    \
        fb0[ni] = *(const f16x8*)&_sb[bfo[ni][ks]];                         \
        fb1[ni] = *(const f16x8*)&_sb[4096 + bfo[ni][ks]];                  \
      }                                                                     \
      __builtin_amdgcn_s_setprio(1);                                        \
      _Pragma("unroll") for (int mi = 0; mi < 2; ++mi)                      \
      _Pragma("unroll") for (int ni = 0; ni < 2; ++ni) {                    \
        acc0[mi][ni] = mfma32(fa0[mi], fb0[ni], acc0[mi][ni]);              \
        acc1[mi][ni] = mfma32(fa0[mi], fb1[ni], acc1[mi][ni]);              \
        acc1[mi][ni] = mfma32(fa1[mi], fb0[ni], acc1[mi][ni]);              \
      }                                                                     \
      __builtin_amdgcn_s_setprio(0);                                        \
    }                                                                       \
  }

// stage one 32-k step: A 2 planes x 2 row-sweeps + B 2 planes x 2 row-sweeps = 8 loads/thread
#define STAGE8(K0, DST, PSA, PSB)                                           \
  {                                                                         \
    _Pragma("unroll") for (int s = 0; s < 2; ++s) {                         \
      gload16(pA + s * (PSA) + (K0), (DST) + s * 4096 + stg);               \
      gload16(pA2 + s * (PSA) + (K0), (DST) + 2048 + s * 4096 + stg);       \
    }                                                                       \
    _Pragma("unroll") for (int s = 0; s < 2; ++s) {                         \
      gload16(pB + s * (PSB) + (K0), (DST) + 8192 + s * 4096 + stg);        \
      gload16(pB2 + s * (PSB) + (K0), (DST) + 10240 + s * 4096 + stg);      \
    }                                                                       \
  }

#define GEMM_PIPELOOP(KTOT, PSA, PSB)                                       \
  STAGE8(0, &SB[0], PSA, PSB);                                              \
  __syncthreads();                                                          \
  {                                                                         \
    int pb = 0;                                                             \
    for (int k0 = 0; k0 < (KTOT); k0 += 32, pb ^= 1) {                      \
      if (k0 + 32 < (KTOT))                                                 \
        STAGE8(k0 + 32, pb ? &SB[0] : &SB[16384], PSA, PSB);                \
      GEMM_COMPUTE(pb ? &SB[16384] : &SB[0]);                               \
      __syncthreads();                                                      \
    }                                                                       \
  }

#define CROW(RG) (((RG) & 3) + 8 * ((RG) >> 2))

// bx-affine XCD map: id = xcd + 8*(ny + NYT*bxs); 16 consecutive same-XCD blocks share
// one A-row-panel (L2-resident) while W panels stream from L3. Requires nbx%8==0.
#define MAPX(ID, NYT, NBX, BX, NY)                                          \
  int BX, NY;                                                               \
  if (((NBX) & 7) == 0) {                                                   \
    int xcd = (ID) & 7, j = (ID) >> 3;                                      \
    NY = j % (NYT); BX = xcd * ((NBX) >> 3) + j / (NYT);                    \
  } else { BX = (ID) / (NYT); NY = (ID) % (NYT); }

// ---------------- layer 1: gather xm2 @ W1T, relu+b1 -> h1 (2-split) ----------------
__global__ __launch_bounds__(256, 2) void k_l1(
    const f16* __restrict__ xm2, const f16* __restrict__ WT,
    const float* __restrict__ b1, f16* __restrict__ h1,
    const int* __restrict__ list, const int* __restrict__ cntp,
    int chunk_off, int chunk_rows) {
  int cnt = *cntp;
  int nbx = gridDim.x >> 4;
  MAPX(blockIdx.x, 16, nbx, bx, ny);
  int lm0 = bx * 128;
  if (chunk_off + lm0 >= cnt) return;
  int lim = cnt - chunk_off; if (lim > chunk_rows) lim = chunk_rows;
  int n0 = ny * 128;

  __shared__ f16 SB[2 * 16384];
  GEMM_PREAMBLE();

  int pu = chunk_off + lm0 + (tid >> 2);
  int pu2 = pu + 64;
  int idx = list[pu < cnt ? pu : (cnt - 1)];
  int idx2 = list[pu2 < cnt ? pu2 : (cnt - 1)];
  const f16* pA = xm2 + (size_t)idx * (2 * NIN) + ksrc;
  const f16* pA2 = xm2 + (size_t)idx2 * (2 * NIN) + ksrc;
  const f16* pB = WT + (size_t)(n0 + (tid >> 2)) * (2 * NIN) + ksrc;
  const f16* pB2 = pB + (size_t)64 * (2 * NIN);

  GEMM_PIPELOOP(NIN, NIN, NIN);

#pragma unroll
  for (int ni = 0; ni < 2; ++ni) {
    int col = n0 + wc * 64 + ni * 32 + l31;
    float bb = b1[col];
#pragma unroll
    for (int mi = 0; mi < 2; ++mi) {
#pragma unroll
      for (int rg = 0; rg < 16; ++rg) {
        int grow = lm0 + wr * 64 + mi * 32 + CROW(rg) + 4 * kg;
        if (grow < lim) {
          float v = fmaxf(acc0[mi][ni][rg] + EPS1 * acc1[mi][ni][rg] + bb, 0.0f);
          f16 a0, a1; split2(v, a0, a1);
          size_t o = (size_t)grow * (2 * NHID) + col;
          h1[o] = a0; h1[o + NHID] = a1;
        }
      }
    }
  }
}

// ---------------- layer 2: h1 @ W2T, relu+b2 -> h2 (2-split) ----------------
__global__ __launch_bounds__(256, 2) void k_l2(
    const f16* __restrict__ h1, const f16* __restrict__ WT,
    const float* __restrict__ b2, f16* __restrict__ h2,
    const int* __restrict__ cntp, int chunk_off, int chunk_rows) {
  int cnt = *cntp;
  int nbx = gridDim.x >> 4;
  MAPX(blockIdx.x, 16, nbx, bx, ny);
  int lm0 = bx * 128;
  if (chunk_off + lm0 >= cnt) return;
  int lim = cnt - chunk_off; if (lim > chunk_rows) lim = chunk_rows;
  int n0 = ny * 128;

  __shared__ f16 SB[2 * 16384];
  GEMM_PREAMBLE();

  const f16* pA = h1 + (size_t)(lm0 + (tid >> 2)) * (2 * NHID) + ksrc;
  const f16* pA2 = pA + (size_t)64 * (2 * NHID);
  const f16* pB = WT + (size_t)(n0 + (tid >> 2)) * (2 * NHID) + ksrc;
  const f16* pB2 = pB + (size_t)64 * (2 * NHID);

  GEMM_PIPELOOP(NHID, NHID, NHID);

#pragma unroll
  for (int ni = 0; ni < 2; ++ni) {
    int col = n0 + wc * 64 + ni * 32 + l31;
    float bb = b2[col];
#pragma unroll
    for (int mi = 0; mi < 2; ++mi) {
#pragma unroll
      for (int rg = 0; rg < 16; ++rg) {
        int grow = lm0 + wr * 64 + mi * 32 + CROW(rg) + 4 * kg;
        if (grow < lim) {
          float v = fmaxf(acc0[mi][ni][rg] + EPS1 * acc1[mi][ni][rg] + bb, 0.0f);
          f16 a0, a1; split2(v, a0, a1);
          size_t o = (size_t)grow * (2 * NHID) + col;
          h2[o] = a0; h2[o + NHID] = a1;
        }
      }
    }
  }
}

// ---------------- layer 3: h2 @ W3T + b3 -> scatter xm2; ny==0 blocks also do halt
// update + compaction inline (probs=col0 / hv=col1 stashed in LDS after the GEMM) ----------------
__global__ __launch_bounds__(256, 2) void k_l3(
    const f16* __restrict__ h2, const f16* __restrict__ WT,
    const float* __restrict__ b3, f16* __restrict__ xm2,
    float* __restrict__ fpb,
    const int* __restrict__ list, int* __restrict__ listn,
    const int* __restrict__ cntp, int* __restrict__ cntn,
    int chunk_off, int chunk_rows) {
  int cnt = *cntp;
  int nbx = gridDim.x / 6;
  MAPX(blockIdx.x, 6, nbx, bx, ny);
  int lm0 = bx * 128;
  if (chunk_off + lm0 >= cnt) return;
  int lim = cnt - chunk_off; if (lim > chunk_rows) lim = chunk_rows;
  int n0 = ny * 128;

  __shared__ f16 SB[2 * 16384];
  GEMM_PREAMBLE();

  const f16* pA = h2 + (size_t)(lm0 + (tid >> 2)) * (2 * NHID) + ksrc;
  const f16* pA2 = pA + (size_t)64 * (2 * NHID);
  const f16* pB = WT + (size_t)(n0 + (tid >> 2)) * (2 * NHID) + ksrc;
  const f16* pB2 = pB + (size_t)64 * (2 * NHID);

  GEMM_PIPELOOP(NHID, NHID, NHID);

  float* SBp = (float*)SB;          // probs[128]  (LDS reuse; GEMM reads done)
  float* SBh = (float*)SB + 128;    // hv[128]

#pragma unroll
  for (int ni = 0; ni < 2; ++ni) {
    int col = n0 + wc * 64 + ni * 32 + l31;
    float bb = (col < NOUT) ? b3[col] : 0.0f;
    if (col >= NOUT) continue;
#pragma unroll
    for (int mi = 0; mi < 2; ++mi) {
#pragma unroll
      for (int rg = 0; rg < 16; ++rg) {
        int grow = lm0 + wr * 64 + mi * 32 + CROW(rg) + 4 * kg;
        if (grow >= lim) continue;
        int r = list[chunk_off + grow];
        float v = acc0[mi][ni][rg] + EPS1 * acc1[mi][ni][rg] + bb;
        if (col == 0) {
          SBp[grow - lm0] = v;
        } else if (col == 1) {
          SBh[grow - lm0] = v;
        } else if (col < 2 + NH) {
          f16 a0, a1; split2(v, a0, a1);
          size_t o = (size_t)r * (2 * NIN) + (col - 2);
          xm2[o] = a0; xm2[o + NIN] = a1;
        } else {
          f16 a0, a1; split2(v, a0, a1);
          size_t o = (size_t)r * (2 * NIN) + 512 + (col - 2 - NH);
          xm2[o] = a0; xm2[o + NIN] = a1;
        }
      }
    }
  }

  if (ny == 0) {
    __syncthreads();
    int rcount = lim - lm0; if (rcount > 128) rcount = 128;
    if (tid < rcount) {
      int r = list[chunk_off + lm0 + tid];
      if (SBh[tid] > 0.0f) {
        fpb[r] = SBp[tid];
      } else {
        int pos = atomicAdd(cntn, 1);
        listn[pos] = r;
      }
    }
  }
}

// ---------------- final ----------------
__global__ void k_final(const float* __restrict__ fpb, float* __restrict__ out) {
  int i = blockIdx.x * blockDim.x + threadIdx.x;
  if (i < NB) {
    out[i] = 1.0f / (1.0f + expf(-fpb[i]));
    out[NB + i] = 0.0f;
  }
}

extern "C" void kernel_launch(void* const* d_in, const int* in_sizes, int n_in,
                              void* d_out, int out_size, void* d_ws, size_t ws_size,
                              hipStream_t stream) {
  const float* x  = (const float*)d_in[0];
  const float* W1 = (const float*)d_in[1];
  const float* b1 = (const float*)d_in[2];
  const float* W2 = (const float*)d_in[3];
  const float* b2 = (const float*)d_in[4];
  const float* W3 = (const float*)d_in[5];
  const float* b3 = (const float*)d_in[6];
  float* out = (float*)d_out;

  char* p = (char*)d_ws;
  auto alloc = [&](size_t bytes) {
    char* r = p;
    p += (bytes + 255) & ~(size_t)255;
    return r;
  };
  f16* xm2  = (f16*)alloc((size_t)NB * 2 * NIN * 2);     // 80 MiB
  f16* W1T  = (f16*)alloc((size_t)NHID * 2 * NIN * 2);   // 5 MiB
  f16* W2T  = (f16*)alloc((size_t)NHID * 2 * NHID * 2);  // 16 MiB
  f16* W3T  = (f16*)alloc((size_t)NOUTP * 2 * NHID * 2); // 6 MiB
  float* fpb   = (float*)alloc((size_t)NB * 4);
  int* list0   = (int*)alloc((size_t)NB * 4);
  int* list1   = (int*)alloc((size_t)NB * 4);
  int* cnt     = (int*)alloc(32 * 4);

  size_t used = (size_t)(p - (char*)d_ws);
  size_t remain = (ws_size > used) ? (ws_size - used) : 0;
  long long chl = (long long)(remain / ((size_t)2 * 2 * NHID * 2)); // h1+h2 = 16384 B/row
  int CH = (int)(chl > NB ? NB : chl);
  CH &= ~127;
  if (CH > 8192) CH = 8192;   // grid = 1024 blocks = exactly 2 scheduling waves (512 slots)
  if (CH < 128) CH = 128;
  f16* h1 = (f16*)alloc((size_t)CH * 2 * NHID * 2);
  f16* h2 = (f16*)alloc((size_t)CH * 2 * NHID * 2);
  int nchunks = (NB + CH - 1) / CH;

  k_prepW<<<dim3(NIN / 32, NHID / 32), 256, 0, stream>>>(W1, W1T, NIN, NHID);
  k_prepW<<<dim3(NHID / 32, NHID / 32), 256, 0, stream>>>(W2, W2T, NHID, NHID);
  k_prepW<<<dim3(NHID / 32, NOUTP / 32), 256, 0, stream>>>(W3, W3T, NHID, NOUT);
  k_splitX<<<(NB * NH) / 256, 256, 0, stream>>>(x, xm2);
  k_init<<<(NB * NM) / 256, 256, 0, stream>>>(xm2, fpb, list0, cnt);

  for (int t = 0; t < ITERS; ++t) {
    const int* lc = (t & 1) ? list1 : list0;
    int* ln       = (t & 1) ? list0 : list1;
    const int* cc = cnt + t;
    int* cn       = cnt + t + 1;
    for (int c = 0; c < nchunks; ++c) {
      int off = c * CH;
      int rows = NB - off; if (rows > CH) rows = CH;
      int g1 = (CH / 128) * 16;
      k_l1<<<g1, 256, 0, stream>>>(xm2, W1T, b1, h1, lc, cc, off, rows);
      k_l2<<<g1, 256, 0, stream>>>(h1, W2T, b2, h2, cc, off, rows);
      int g3 = (CH / 128) * 6;
      k_l3<<<g3, 256, 0, stream>>>(h2, W3T, b3, xm2, fpb, lc, ln, cc, cn, off, rows);
    }
  }
  k_final<<<NB / 256, 256, 0, stream>>>(fpb, out);
}

// Round 14
// 3962.425 us; speedup vs baseline: 1.1423x; 1.1423x over previous
//
#include <hip/hip_runtime.h>
#include <math.h>

typedef _Float16 f16;
typedef _Float16 f16x8 __attribute__((ext_vector_type(8)));
typedef float f32x4 __attribute__((ext_vector_type(4)));

#define NB 32768
#define NH 512
#define NM 128
#define NIN 640
#define NHID 2048
#define NOUT 642
#define NOUTP 768
#define ITERS 16
// 2-split f16: v = a0 + a1*EPS1,  EPS1=2^-11
#define S1 2048.0f
#define EPS1 4.8828125e-4f

__device__ __forceinline__ void gload16(const void* g, void* lds) {
  __builtin_amdgcn_global_load_lds(
      reinterpret_cast<const __attribute__((address_space(1))) unsigned int*>((uintptr_t)g),
      reinterpret_cast<__attribute__((address_space(3))) unsigned int*>((unsigned int)(uintptr_t)lds),
      16, 0, 0);
}

__device__ __forceinline__ f32x4 mfma16(f16x8 a, f16x8 b, f32x4 c) {
  return __builtin_amdgcn_mfma_f32_16x16x32_f16(a, b, c, 0, 0, 0);
}

__device__ __forceinline__ void split2(float v, f16& a0, f16& a1) {
  a0 = (f16)v;
  a1 = (f16)((v - (float)a0) * S1);
}

// ---------------- weight transpose + 2-split: W[K][Nreal] -> WT[n][2][K] ----------------
__global__ void k_prepW(const float* __restrict__ W, f16* __restrict__ WT,
                        int K, int Nreal) {
  __shared__ float tile[32][33];
  int k0 = blockIdx.x * 32, n0 = blockIdx.y * 32;
  int tx = threadIdx.x & 31, ty = threadIdx.x >> 5;
#pragma unroll
  for (int r = 0; r < 4; ++r) {
    int kk = ty + 8 * r;
    int n = n0 + tx;
    tile[kk][tx] = (n < Nreal) ? W[(size_t)(k0 + kk) * Nreal + n] : 0.0f;
  }
  __syncthreads();
#pragma unroll
  for (int r = 0; r < 4; ++r) {
    int nl = ty + 8 * r;
    float v = tile[tx][nl];
    f16 a0, a1; split2(v, a0, a1);
    size_t o = (size_t)(n0 + nl) * (2 * K) + k0 + tx;
    WT[o] = a0; WT[o + K] = a1;
  }
}

// ---------------- split x into merged state xm2[row][2][640] (x cols 0..511) ----------------
__global__ void k_splitX(const float* __restrict__ x, f16* __restrict__ xm2) {
  int i = blockIdx.x * 256 + threadIdx.x;
  int row = i >> 9, c = i & 511;
  f16 a0, a1; split2(x[i], a0, a1);
  size_t o = (size_t)row * (2 * NIN) + c;
  xm2[o] = a0; xm2[o + NIN] = a1;
}

// ---------------- init mem part of xm2 (cols 512..639), fp/list/cnt ----------------
__global__ void k_init(f16* __restrict__ xm2, float* __restrict__ fpb,
                       int* __restrict__ list0, int* __restrict__ cnt) {
  int gid = blockIdx.x * blockDim.x + threadIdx.x;
  if (gid < NB * NM) {
    int row = gid >> 7, c = gid & 127;
    size_t o = (size_t)row * (2 * NIN) + 512 + c;
    xm2[o] = (f16)((c == 0) ? 16.0f : 0.0f);
    xm2[o + NIN] = (f16)0.0f;
  }
  if (gid < NB) { fpb[gid] = 0.0f; list0[gid] = gid; }
  if (gid < 32) cnt[gid] = (gid == 0) ? NB : 0;
}

// ===== GEMM: 128x128 tile, BK=32, 256 thr = 4 waves (2x2), wave tile 64x64, 3-pass 2-split =====
// MFMA 16x16x32 (r11-verified: 0 bank conflicts, ~981 TF in k_l2; r12/r13's 32x32 shape
// had an irreducible ~2^24 conflict count under two different swizzles -> reverted).
// LDS per buffer: A planes 128x32 @ {0,4096}, B planes @ {8192,12288} f16; dbuf 64 KB -> 2 blk/CU.

#define GEMM_PREAMBLE()                                                     \
  int tid = threadIdx.x;                                                    \
  int w = tid >> 6, lane = tid & 63;                                        \
  int wr = w >> 1, wc = w & 1;                                              \
  int lm = lane & 15, kb = lane >> 4;                                       \
  int kidx = ((kb ^ ((lm >> 1) & 3)) << 3);                                 \
  int ksrc = (((tid & 3) ^ ((tid >> 3) & 3)) << 3);                         \
  int stg = tid * 8;                                                        \
  int afo[4], bfo[4];                                                       \
  _Pragma("unroll") for (int m = 0; m < 4; ++m)                             \
    afo[m] = (wr * 64 + m * 16 + lm) * 32 + kidx;                           \
  _Pragma("unroll") for (int n = 0; n < 4; ++n)                             \
    bfo[n] = (wc * 64 + n * 16 + lm) * 32 + kidx + 8192;                    \
  f32x4 acc0[4][4], acc1[4][4];                                             \
  _Pragma("unroll") for (int m = 0; m < 4; ++m)                             \
  _Pragma("unroll") for (int n = 0; n < 4; ++n) {                           \
    acc0[m][n] = (f32x4)0.0f; acc1[m][n] = (f32x4)0.0f;                     \
  }

#define GEMM_COMPUTE(BASE)                                                  \
  {                                                                         \
    const f16* _sb = (BASE);                                                \
    f16x8 fa0[4], fa1[4], fb0[4], fb1[4];                                   \
    _Pragma("unroll") for (int m = 0; m < 4; ++m) {                         \
      fa0[m] = *(const f16x8*)&_sb[afo[m]];                                 \
      fa1[m] = *(const f16x8*)&_sb[4096 + afo[m]];                          \
    }                                                                       \
    _Pragma("unroll") for (int n = 0; n < 4; ++n) {                         \
      fb0[n] = *(const f16x8*)&_sb[bfo[n]];                                 \
      fb1[n] = *(const f16x8*)&_sb[4096 + bfo[n]];                          \
    }                                                                       \
    __builtin_amdgcn_s_setprio(1);                                          \
    _Pragma("unroll") for (int m = 0; m < 4; ++m)                           \
    _Pragma("unroll") for (int n = 0; n < 4; ++n) {                         \
      acc0[m][n] = mfma16(fa0[m], fb0[n], acc0[m][n]);                      \
      acc1[m][n] = mfma16(fa0[m], fb1[n], acc1[m][n]);                      \
      acc1[m][n] = mfma16(fa1[m], fb0[n], acc1[m][n]);                      \
    }                                                                       \
    __builtin_amdgcn_s_setprio(0);                                          \
  }

// stage one 32-k step: A 2 planes x 2 row-sweeps + B 2 planes x 2 row-sweeps = 8 loads/thread
#define STAGE8(K0, DST, PSA, PSB)                                           \
  {                                                                         \
    _Pragma("unroll") for (int s = 0; s < 2; ++s) {                         \
      gload16(pA + s * (PSA) + (K0), (DST) + s * 4096 + stg);               \
      gload16(pA2 + s * (PSA) + (K0), (DST) + 2048 + s * 4096 + stg);       \
    }                                                                       \
    _Pragma("unroll") for (int s = 0; s < 2; ++s) {                         \
      gload16(pB + s * (PSB) + (K0), (DST) + 8192 + s * 4096 + stg);        \
      gload16(pB2 + s * (PSB) + (K0), (DST) + 10240 + s * 4096 + stg);      \
    }                                                                       \
  }

#define GEMM_PIPELOOP(KTOT, PSA, PSB)                                       \
  STAGE8(0, &SB[0], PSA, PSB);                                              \
  __syncthreads();                                                          \
  {                                                                         \
    int pb = 0;                                                             \
    for (int k0 = 0; k0 < (KTOT); k0 += 32, pb ^= 1) {                      \
      if (k0 + 32 < (KTOT))                                                 \
        STAGE8(k0 + 32, pb ? &SB[0] : &SB[16384], PSA, PSB);                \
      GEMM_COMPUTE(pb ? &SB[16384] : &SB[0]);                               \
      __syncthreads();                                                      \
    }                                                                       \
  }

#define COMBINE(m, n, q) (acc0[m][n][q] + EPS1 * acc1[m][n][q])

// bx-affine XCD map (ONLY change vs r11): id = xcd + 8*(ny + NYT*bxs); 16 consecutive
// same-XCD blocks share one A-row-panel (1 MB, L2-resident) while W streams from L3.
// r12/r13 evidence: FETCH_SIZE 286 -> ~255 MB. Requires nbx%8==0 (CH=8192 -> nbx=64 ok).
#define MAPX(ID, NYT, NBX, BX, NY)                                          \
  int BX, NY;                                                               \
  if (((NBX) & 7) == 0) {                                                   \
    int xcd = (ID) & 7, j = (ID) >> 3;                                      \
    NY = j % (NYT); BX = xcd * ((NBX) >> 3) + j / (NYT);                    \
  } else { BX = (ID) / (NYT); NY = (ID) % (NYT); }

// ---------------- layer 1: gather xm2 @ W1T, relu+b1 -> h1 (2-split) ----------------
__global__ __launch_bounds__(256, 2) void k_l1(
    const f16* __restrict__ xm2, const f16* __restrict__ WT,
    const float* __restrict__ b1, f16* __restrict__ h1,
    const int* __restrict__ list, const int* __restrict__ cntp,
    int chunk_off, int chunk_rows) {
  int cnt = *cntp;
  int nbx = gridDim.x >> 4;
  MAPX(blockIdx.x, 16, nbx, bx, ny);
  int lm0 = bx * 128;
  if (chunk_off + lm0 >= cnt) return;
  int lim = cnt - chunk_off; if (lim > chunk_rows) lim = chunk_rows;
  int n0 = ny * 128;

  __shared__ f16 SB[2 * 16384];
  GEMM_PREAMBLE();

  int pu = chunk_off + lm0 + (tid >> 2);
  int pu2 = pu + 64;
  int idx = list[pu < cnt ? pu : (cnt - 1)];
  int idx2 = list[pu2 < cnt ? pu2 : (cnt - 1)];
  const f16* pA = xm2 + (size_t)idx * (2 * NIN) + ksrc;
  const f16* pA2 = xm2 + (size_t)idx2 * (2 * NIN) + ksrc;
  const f16* pB = WT + (size_t)(n0 + (tid >> 2)) * (2 * NIN) + ksrc;
  const f16* pB2 = pB + (size_t)64 * (2 * NIN);

  GEMM_PIPELOOP(NIN, NIN, NIN);

#pragma unroll
  for (int n = 0; n < 4; ++n) {
    int col = n0 + wc * 64 + n * 16 + lm;
    float bb = b1[col];
#pragma unroll
    for (int m = 0; m < 4; ++m) {
#pragma unroll
      for (int q = 0; q < 4; ++q) {
        int gr = lm0 + wr * 64 + m * 16 + kb * 4 + q;
        if (gr < lim) {
          float v = fmaxf(COMBINE(m, n, q) + bb, 0.0f);
          f16 a0, a1; split2(v, a0, a1);
          size_t o = (size_t)gr * (2 * NHID) + col;
          h1[o] = a0; h1[o + NHID] = a1;
        }
      }
    }
  }
}

// ---------------- layer 2: h1 @ W2T, relu+b2 -> h2 (2-split) ----------------
__global__ __launch_bounds__(256, 2) void k_l2(
    const f16* __restrict__ h1, const f16* __restrict__ WT,
    const float* __restrict__ b2, f16* __restrict__ h2,
    const int* __restrict__ cntp, int chunk_off, int chunk_rows) {
  int cnt = *cntp;
  int nbx = gridDim.x >> 4;
  MAPX(blockIdx.x, 16, nbx, bx, ny);
  int lm0 = bx * 128;
  if (chunk_off + lm0 >= cnt) return;
  int lim = cnt - chunk_off; if (lim > chunk_rows) lim = chunk_rows;
  int n0 = ny * 128;

  __shared__ f16 SB[2 * 16384];
  GEMM_PREAMBLE();

  const f16* pA = h1 + (size_t)(lm0 + (tid >> 2)) * (2 * NHID) + ksrc;
  const f16* pA2 = pA + (size_t)64 * (2 * NHID);
  const f16* pB = WT + (size_t)(n0 + (tid >> 2)) * (2 * NHID) + ksrc;
  const f16* pB2 = pB + (size_t)64 * (2 * NHID);

  GEMM_PIPELOOP(NHID, NHID, NHID);

#pragma unroll
  for (int n = 0; n < 4; ++n) {
    int col = n0 + wc * 64 + n * 16 + lm;
    float bb = b2[col];
#pragma unroll
    for (int m = 0; m < 4; ++m) {
#pragma unroll
      for (int q = 0; q < 4; ++q) {
        int gr = lm0 + wr * 64 + m * 16 + kb * 4 + q;
        if (gr < lim) {
          float v = fmaxf(COMBINE(m, n, q) + bb, 0.0f);
          f16 a0, a1; split2(v, a0, a1);
          size_t o = (size_t)gr * (2 * NHID) + col;
          h2[o] = a0; h2[o + NHID] = a1;
        }
      }
    }
  }
}

// ---------------- layer 3: h2 @ W3T + b3 -> scatter xm2; ny==0 blocks also do halt
// update + compaction inline (probs=col0 / hv=col1 stashed in LDS after the GEMM) ----------------
__global__ __launch_bounds__(256, 2) void k_l3(
    const f16* __restrict__ h2, const f16* __restrict__ WT,
    const float* __restrict__ b3, f16* __restrict__ xm2,
    float* __restrict__ fpb,
    const int* __restrict__ list, int* __restrict__ listn,
    const int* __restrict__ cntp, int* __restrict__ cntn,
    int chunk_off, int chunk_rows) {
  int cnt = *cntp;
  int nbx = gridDim.x / 6;
  MAPX(blockIdx.x, 6, nbx, bx, ny);
  int lm0 = bx * 128;
  if (chunk_off + lm0 >= cnt) return;
  int lim = cnt - chunk_off; if (lim > chunk_rows) lim = chunk_rows;
  int n0 = ny * 128;

  __shared__ f16 SB[2 * 16384];
  GEMM_PREAMBLE();

  const f16* pA = h2 + (size_t)(lm0 + (tid >> 2)) * (2 * NHID) + ksrc;
  const f16* pA2 = pA + (size_t)64 * (2 * NHID);
  const f16* pB = WT + (size_t)(n0 + (tid >> 2)) * (2 * NHID) + ksrc;
  const f16* pB2 = pB + (size_t)64 * (2 * NHID);

  GEMM_PIPELOOP(NHID, NHID, NHID);

  float* SBp = (float*)SB;          // probs[128]  (LDS reuse; GEMM reads done)
  float* SBh = (float*)SB + 128;    // hv[128]

  float bb[4]; int colv[4];
#pragma unroll
  for (int n = 0; n < 4; ++n) {
    colv[n] = n0 + wc * 64 + n * 16 + lm;
    bb[n] = (colv[n] < NOUT) ? b3[colv[n]] : 0.0f;
  }
#pragma unroll
  for (int m = 0; m < 4; ++m) {
#pragma unroll
    for (int q = 0; q < 4; ++q) {
      int gr = lm0 + wr * 64 + m * 16 + kb * 4 + q;
      if (gr >= lim) continue;
      int r = list[chunk_off + gr];
#pragma unroll
      for (int n = 0; n < 4; ++n) {
        int col = colv[n];
        if (col >= NOUT) continue;
        float v = COMBINE(m, n, q) + bb[n];
        if (col == 0) {
          SBp[gr - lm0] = v;
        } else if (col == 1) {
          SBh[gr - lm0] = v;
        } else if (col < 2 + NH) {
          f16 a0, a1; split2(v, a0, a1);
          size_t o = (size_t)r * (2 * NIN) + (col - 2);
          xm2[o] = a0; xm2[o + NIN] = a1;
        } else {
          f16 a0, a1; split2(v, a0, a1);
          size_t o = (size_t)r * (2 * NIN) + 512 + (col - 2 - NH);
          xm2[o] = a0; xm2[o + NIN] = a1;
        }
      }
    }
  }

  if (ny == 0) {
    __syncthreads();
    int rcount = lim - lm0; if (rcount > 128) rcount = 128;
    if (tid < rcount) {
      int r = list[chunk_off + lm0 + tid];
      if (SBh[tid] > 0.0f) {
        fpb[r] = SBp[tid];
      } else {
        int pos = atomicAdd(cntn, 1);
        listn[pos] = r;
      }
    }
  }
}

// ---------------- final ----------------
__global__ void k_final(const float* __restrict__ fpb, float* __restrict__ out) {
  int i = blockIdx.x * blockDim.x + threadIdx.x;
  if (i < NB) {
    out[i] = 1.0f / (1.0f + expf(-fpb[i]));
    out[NB + i] = 0.0f;
  }
}

extern "C" void kernel_launch(void* const* d_in, const int* in_sizes, int n_in,
                              void* d_out, int out_size, void* d_ws, size_t ws_size,
                              hipStream_t stream) {
  const float* x  = (const float*)d_in[0];
  const float* W1 = (const float*)d_in[1];
  const float* b1 = (const float*)d_in[2];
  const float* W2 = (const float*)d_in[3];
  const float* b2 = (const float*)d_in[4];
  const float* W3 = (const float*)d_in[5];
  const float* b3 = (const float*)d_in[6];
  float* out = (float*)d_out;

  char* p = (char*)d_ws;
  auto alloc = [&](size_t bytes) {
    char* r = p;
    p += (bytes + 255) & ~(size_t)255;
    return r;
  };
  f16* xm2  = (f16*)alloc((size_t)NB * 2 * NIN * 2);     // 80 MiB
  f16* W1T  = (f16*)alloc((size_t)NHID * 2 * NIN * 2);   // 5 MiB
  f16* W2T  = (f16*)alloc((size_t)NHID * 2 * NHID * 2);  // 16 MiB
  f16* W3T  = (f16*)alloc((size_t)NOUTP * 2 * NHID * 2); // 6 MiB
  float* fpb   = (float*)alloc((size_t)NB * 4);
  int* list0   = (int*)alloc((size_t)NB * 4);
  int* list1   = (int*)alloc((size_t)NB * 4);
  int* cnt     = (int*)alloc(32 * 4);

  size_t used = (size_t)(p - (char*)d_ws);
  size_t remain = (ws_size > used) ? (ws_size - used) : 0;
  long long chl = (long long)(remain / ((size_t)2 * 2 * NHID * 2)); // h1+h2 = 16384 B/row
  int CH = (int)(chl > NB ? NB : chl);
  CH &= ~127;
  if (CH > 8192) CH = 8192;   // grid = 1024 blocks = exactly 2 scheduling waves (512 slots)
  if (CH < 128) CH = 128;
  f16* h1 = (f16*)alloc((size_t)CH * 2 * NHID * 2);
  f16* h2 = (f16*)alloc((size_t)CH * 2 * NHID * 2);
  int nchunks = (NB + CH - 1) / CH;

  k_prepW<<<dim3(NIN / 32, NHID / 32), 256, 0, stream>>>(W1, W1T, NIN, NHID);
  k_prepW<<<dim3(NHID / 32, NHID / 32), 256, 0, stream>>>(W2, W2T, NHID, NHID);
  k_prepW<<<dim3(NHID / 32, NOUTP / 32), 256, 0, stream>>>(W3, W3T, NHID, NOUT);
  k_splitX<<<(NB * NH) / 256, 256, 0, stream>>>(x, xm2);
  k_init<<<(NB * NM) / 256, 256, 0, stream>>>(xm2, fpb, list0, cnt);

  for (int t = 0; t < ITERS; ++t) {
    const int* lc = (t & 1) ? list1 : list0;
    int* ln       = (t & 1) ? list0 : list1;
    const int* cc = cnt + t;
    int* cn       = cnt + t + 1;
    for (int c = 0; c < nchunks; ++c) {
      int off = c * CH;
      int rows = NB - off; if (rows > CH) rows = CH;
      int g1 = (CH / 128) * 16;
      k_l1<<<g1, 256, 0, stream>>>(xm2, W1T, b1, h1, lc, cc, off, rows);
      k_l2<<<g1, 256, 0, stream>>>(h1, W2T, b2, h2, cc, off, rows);
      int g3 = (CH / 128) * 6;
      k_l3<<<g3, 256, 0, stream>>>(h2, W3T, b3, xm2, fpb, lc, ln, cc, cn, off, rows);
    }
  }
  k_final<<<NB / 256, 256, 0, stream>>>(fpb, out);
}

// Round 15
// 3877.313 us; speedup vs baseline: 1.1674x; 1.0220x over previous
//
#include <hip/hip_runtime.h>
#include <math.h>

typedef _Float16 f16;
typedef _Float16 f16x8 __attribute__((ext_vector_type(8)));
typedef float f32x4 __attribute__((ext_vector_type(4)));

#define NB 32768
#define NH 512
#define NM 128
#define NIN 640
#define NHID 2048
#define NOUT 642
#define NOUTP 768
#define ITERS 16
// 2-split f16: v = a0 + a1*EPS1,  EPS1=2^-11
#define S1 2048.0f
#define EPS1 4.8828125e-4f

__device__ __forceinline__ void gload16(const void* g, void* lds) {
  __builtin_amdgcn_global_load_lds(
      reinterpret_cast<const __attribute__((address_space(1))) unsigned int*>((uintptr_t)g),
      reinterpret_cast<__attribute__((address_space(3))) unsigned int*>((unsigned int)(uintptr_t)lds),
      16, 0, 0);
}

__device__ __forceinline__ f32x4 mfma16(f16x8 a, f16x8 b, f32x4 c) {
  return __builtin_amdgcn_mfma_f32_16x16x32_f16(a, b, c, 0, 0, 0);
}

__device__ __forceinline__ void split2(float v, f16& a0, f16& a1) {
  a0 = (f16)v;
  a1 = (f16)((v - (float)a0) * S1);
}

// ---------------- weight transpose + 2-split: W[K][Nreal] -> WT[n][2][K] ----------------
__global__ void k_prepW(const float* __restrict__ W, f16* __restrict__ WT,
                        int K, int Nreal) {
  __shared__ float tile[32][33];
  int k0 = blockIdx.x * 32, n0 = blockIdx.y * 32;
  int tx = threadIdx.x & 31, ty = threadIdx.x >> 5;
#pragma unroll
  for (int r = 0; r < 4; ++r) {
    int kk = ty + 8 * r;
    int n = n0 + tx;
    tile[kk][tx] = (n < Nreal) ? W[(size_t)(k0 + kk) * Nreal + n] : 0.0f;
  }
  __syncthreads();
#pragma unroll
  for (int r = 0; r < 4; ++r) {
    int nl = ty + 8 * r;
    float v = tile[tx][nl];
    f16 a0, a1; split2(v, a0, a1);
    size_t o = (size_t)(n0 + nl) * (2 * K) + k0 + tx;
    WT[o] = a0; WT[o + K] = a1;
  }
}

// ---------------- split x into merged state xm2[row][2][640] (x cols 0..511) ----------------
__global__ void k_splitX(const float* __restrict__ x, f16* __restrict__ xm2) {
  int i = blockIdx.x * 256 + threadIdx.x;
  int row = i >> 9, c = i & 511;
  f16 a0, a1; split2(x[i], a0, a1);
  size_t o = (size_t)row * (2 * NIN) + c;
  xm2[o] = a0; xm2[o + NIN] = a1;
}

// ---------------- init mem part of xm2 (cols 512..639), fp/list/cnt ----------------
__global__ void k_init(f16* __restrict__ xm2, float* __restrict__ fpb,
                       int* __restrict__ list0, int* __restrict__ cnt) {
  int gid = blockIdx.x * blockDim.x + threadIdx.x;
  if (gid < NB * NM) {
    int row = gid >> 7, c = gid & 127;
    size_t o = (size_t)row * (2 * NIN) + 512 + c;
    xm2[o] = (f16)((c == 0) ? 16.0f : 0.0f);
    xm2[o + NIN] = (f16)0.0f;
  }
  if (gid < NB) { fpb[gid] = 0.0f; list0[gid] = gid; }
  if (gid < 32) cnt[gid] = (gid == 0) ? NB : 0;
}

// ===== GEMM: 128x128 tile, BK=32, 256 thr = 4 waves (2x2), wave tile 64x64, 3-pass 2-split =====
// LDS per buffer: A planes 128x32 @ {0,4096}, B planes 128x32 @ {8192,12288} (f16 units).
// Buffer stride 16384 f16 (32 KB); double-buffered 64 KB -> 2 blocks/CU.
// r11-verified best: 0 bank conflicts, ~981 TF in k_l2, total 3881 us.

#define GEMM_PREAMBLE()                                                     \
  int tid = threadIdx.x;                                                    \
  int w = tid >> 6, lane = tid & 63;                                        \
  int wr = w >> 1, wc = w & 1;                                              \
  int lm = lane & 15, kb = lane >> 4;                                       \
  int kidx = ((kb ^ ((lm >> 1) & 3)) << 3);                                 \
  int ksrc = (((tid & 3) ^ ((tid >> 3) & 3)) << 3);                         \
  int stg = tid * 8;                                                        \
  int afo[4], bfo[4];                                                       \
  _Pragma("unroll") for (int m = 0; m < 4; ++m)                             \
    afo[m] = (wr * 64 + m * 16 + lm) * 32 + kidx;                           \
  _Pragma("unroll") for (int n = 0; n < 4; ++n)                             \
    bfo[n] = (wc * 64 + n * 16 + lm) * 32 + kidx + 8192;                    \
  f32x4 acc0[4][4], acc1[4][4];                                             \
  _Pragma("unroll") for (int m = 0; m < 4; ++m)                             \
  _Pragma("unroll") for (int n = 0; n < 4; ++n) {                           \
    acc0[m][n] = (f32x4)0.0f; acc1[m][n] = (f32x4)0.0f;                     \
  }

#define GEMM_COMPUTE(BASE)                                                  \
  {                                                                         \
    const f16* _sb = (BASE);                                                \
    f16x8 fa0[4], fa1[4], fb0[4], fb1[4];                                   \
    _Pragma("unroll") for (int m = 0; m < 4; ++m) {                         \
      fa0[m] = *(const f16x8*)&_sb[afo[m]];                                 \
      fa1[m] = *(const f16x8*)&_sb[4096 + afo[m]];                          \
    }                                                                       \
    _Pragma("unroll") for (int n = 0; n < 4; ++n) {                         \
      fb0[n] = *(const f16x8*)&_sb[bfo[n]];                                 \
      fb1[n] = *(const f16x8*)&_sb[4096 + bfo[n]];                          \
    }                                                                       \
    __builtin_amdgcn_s_setprio(1);                                          \
    _Pragma("unroll") for (int m = 0; m < 4; ++m)                           \
    _Pragma("unroll") for (int n = 0; n < 4; ++n) {                         \
      acc0[m][n] = mfma16(fa0[m], fb0[n], acc0[m][n]);                      \
      acc1[m][n] = mfma16(fa0[m], fb1[n], acc1[m][n]);                      \
      acc1[m][n] = mfma16(fa1[m], fb0[n], acc1[m][n]);                      \
    }                                                                       \
    __builtin_amdgcn_s_setprio(0);                                          \
  }

// stage one 32-k step: A 2 planes x 2 row-sweeps + B 2 planes x 2 row-sweeps = 8 loads/thread
#define STAGE8(K0, DST, PSA, PSB)                                           \
  {                                                                         \
    _Pragma("unroll") for (int s = 0; s < 2; ++s) {                         \
      gload16(pA + s * (PSA) + (K0), (DST) + s * 4096 + stg);               \
      gload16(pA2 + s * (PSA) + (K0), (DST) + 2048 + s * 4096 + stg);       \
    }                                                                       \
    _Pragma("unroll") for (int s = 0; s < 2; ++s) {                         \
      gload16(pB + s * (PSB) + (K0), (DST) + 8192 + s * 4096 + stg);        \
      gload16(pB2 + s * (PSB) + (K0), (DST) + 10240 + s * 4096 + stg);      \
    }                                                                       \
  }

#define GEMM_PIPELOOP(KTOT, PSA, PSB)                                       \
  STAGE8(0, &SB[0], PSA, PSB);                                              \
  __syncthreads();                                                          \
  {                                                                         \
    int pb = 0;                                                             \
    for (int k0 = 0; k0 < (KTOT); k0 += 32, pb ^= 1) {                      \
      if (k0 + 32 < (KTOT))                                                 \
        STAGE8(k0 + 32, pb ? &SB[0] : &SB[16384], PSA, PSB);                \
      GEMM_COMPUTE(pb ? &SB[16384] : &SB[0]);                               \
      __syncthreads();                                                      \
    }                                                                       \
  }

#define COMBINE(m, n, q) (acc0[m][n][q] + EPS1 * acc1[m][n][q])

// XCD-affine swizzle for 16 col-tiles (r11-verified best map):
// ny = (id&7) + 8*bit3 -> each XCD owns 2 weight panels
#define MAP16(ID, BX, NY) int NY = ((ID) & 7) + 8 * (((ID) >> 3) & 1); int BX = (ID) >> 4;

// ---------------- layer 1: gather xm2 @ W1T, relu+b1 -> h1 (2-split) ----------------
__global__ __launch_bounds__(256, 2) void k_l1(
    const f16* __restrict__ xm2, const f16* __restrict__ WT,
    const float* __restrict__ b1, f16* __restrict__ h1,
    const int* __restrict__ list, const int* __restrict__ cntp,
    int chunk_off, int chunk_rows) {
  int cnt = *cntp;
  MAP16(blockIdx.x, bx, ny);
  int lm0 = bx * 128;
  if (chunk_off + lm0 >= cnt) return;
  int lim = cnt - chunk_off; if (lim > chunk_rows) lim = chunk_rows;
  int n0 = ny * 128;

  __shared__ f16 SB[2 * 16384];
  GEMM_PREAMBLE();

  int pu = chunk_off + lm0 + (tid >> 2);
  int pu2 = pu + 64;
  int idx = list[pu < cnt ? pu : (cnt - 1)];
  int idx2 = list[pu2 < cnt ? pu2 : (cnt - 1)];
  const f16* pA = xm2 + (size_t)idx * (2 * NIN) + ksrc;
  const f16* pA2 = xm2 + (size_t)idx2 * (2 * NIN) + ksrc;
  const f16* pB = WT + (size_t)(n0 + (tid >> 2)) * (2 * NIN) + ksrc;
  const f16* pB2 = pB + (size_t)64 * (2 * NIN);

  GEMM_PIPELOOP(NIN, NIN, NIN);

#pragma unroll
  for (int n = 0; n < 4; ++n) {
    int col = n0 + wc * 64 + n * 16 + lm;
    float bb = b1[col];
#pragma unroll
    for (int m = 0; m < 4; ++m) {
#pragma unroll
      for (int q = 0; q < 4; ++q) {
        int gr = lm0 + wr * 64 + m * 16 + kb * 4 + q;
        if (gr < lim) {
          float v = fmaxf(COMBINE(m, n, q) + bb, 0.0f);
          f16 a0, a1; split2(v, a0, a1);
          size_t o = (size_t)gr * (2 * NHID) + col;
          h1[o] = a0; h1[o + NHID] = a1;
        }
      }
    }
  }
}

// ---------------- layer 2: h1 @ W2T, relu+b2 -> h2 (2-split) ----------------
__global__ __launch_bounds__(256, 2) void k_l2(
    const f16* __restrict__ h1, const f16* __restrict__ WT,
    const float* __restrict__ b2, f16* __restrict__ h2,
    const int* __restrict__ cntp, int chunk_off, int chunk_rows) {
  int cnt = *cntp;
  MAP16(blockIdx.x, bx, ny);
  int lm0 = bx * 128;
  if (chunk_off + lm0 >= cnt) return;
  int lim = cnt - chunk_off; if (lim > chunk_rows) lim = chunk_rows;
  int n0 = ny * 128;

  __shared__ f16 SB[2 * 16384];
  GEMM_PREAMBLE();

  const f16* pA = h1 + (size_t)(lm0 + (tid >> 2)) * (2 * NHID) + ksrc;
  const f16* pA2 = pA + (size_t)64 * (2 * NHID);
  const f16* pB = WT + (size_t)(n0 + (tid >> 2)) * (2 * NHID) + ksrc;
  const f16* pB2 = pB + (size_t)64 * (2 * NHID);

  GEMM_PIPELOOP(NHID, NHID, NHID);

#pragma unroll
  for (int n = 0; n < 4; ++n) {
    int col = n0 + wc * 64 + n * 16 + lm;
    float bb = b2[col];
#pragma unroll
    for (int m = 0; m < 4; ++m) {
#pragma unroll
      for (int q = 0; q < 4; ++q) {
        int gr = lm0 + wr * 64 + m * 16 + kb * 4 + q;
        if (gr < lim) {
          float v = fmaxf(COMBINE(m, n, q) + bb, 0.0f);
          f16 a0, a1; split2(v, a0, a1);
          size_t o = (size_t)gr * (2 * NHID) + col;
          h2[o] = a0; h2[o + NHID] = a1;
        }
      }
    }
  }
}

// ---------------- layer 3: h2 @ W3T + b3 -> scatter xm2; ny==0 blocks also do halt
// update + compaction inline (probs=col0 / hv=col1 stashed in LDS after the GEMM) ----------------
__global__ __launch_bounds__(256, 2) void k_l3(
    const f16* __restrict__ h2, const f16* __restrict__ WT,
    const float* __restrict__ b3, f16* __restrict__ xm2,
    float* __restrict__ fpb,
    const int* __restrict__ list, int* __restrict__ listn,
    const int* __restrict__ cntp, int* __restrict__ cntn,
    int chunk_off, int chunk_rows) {
  int cnt = *cntp;
  int id = blockIdx.x;
  int bx = id / 6, ny = id - bx * 6;
  int lm0 = bx * 128;
  if (chunk_off + lm0 >= cnt) return;
  int lim = cnt - chunk_off; if (lim > chunk_rows) lim = chunk_rows;
  int n0 = ny * 128;

  __shared__ f16 SB[2 * 16384];
  GEMM_PREAMBLE();

  const f16* pA = h2 + (size_t)(lm0 + (tid >> 2)) * (2 * NHID) + ksrc;
  const f16* pA2 = pA + (size_t)64 * (2 * NHID);
  const f16* pB = WT + (size_t)(n0 + (tid >> 2)) * (2 * NHID) + ksrc;
  const f16* pB2 = pB + (size_t)64 * (2 * NHID);

  GEMM_PIPELOOP(NHID, NHID, NHID);

  float* SBp = (float*)SB;          // probs[128]  (LDS reuse; GEMM reads done)
  float* SBh = (float*)SB + 128;    // hv[128]

  float bb[4]; int colv[4];
#pragma unroll
  for (int n = 0; n < 4; ++n) {
    colv[n] = n0 + wc * 64 + n * 16 + lm;
    bb[n] = (colv[n] < NOUT) ? b3[colv[n]] : 0.0f;
  }
#pragma unroll
  for (int m = 0; m < 4; ++m) {
#pragma unroll
    for (int q = 0; q < 4; ++q) {
      int gr = lm0 + wr * 64 + m * 16 + kb * 4 + q;
      if (gr >= lim) continue;
      int r = list[chunk_off + gr];
#pragma unroll
      for (int n = 0; n < 4; ++n) {
        int col = colv[n];
        if (col >= NOUT) continue;
        float v = COMBINE(m, n, q) + bb[n];
        if (col == 0) {
          SBp[gr - lm0] = v;
        } else if (col == 1) {
          SBh[gr - lm0] = v;
        } else if (col < 2 + NH) {
          f16 a0, a1; split2(v, a0, a1);
          size_t o = (size_t)r * (2 * NIN) + (col - 2);
          xm2[o] = a0; xm2[o + NIN] = a1;
        } else {
          f16 a0, a1; split2(v, a0, a1);
          size_t o = (size_t)r * (2 * NIN) + 512 + (col - 2 - NH);
          xm2[o] = a0; xm2[o + NIN] = a1;
        }
      }
    }
  }

  if (ny == 0) {
    __syncthreads();
    int rcount = lim - lm0; if (rcount > 128) rcount = 128;
    if (tid < rcount) {
      int r = list[chunk_off + lm0 + tid];
      if (SBh[tid] > 0.0f) {
        fpb[r] = SBp[tid];
      } else {
        int pos = atomicAdd(cntn, 1);
        listn[pos] = r;
      }
    }
  }
}

// ---------------- final ----------------
__global__ void k_final(const float* __restrict__ fpb, float* __restrict__ out) {
  int i = blockIdx.x * blockDim.x + threadIdx.x;
  if (i < NB) {
    out[i] = 1.0f / (1.0f + expf(-fpb[i]));
    out[NB + i] = 0.0f;
  }
}

extern "C" void kernel_launch(void* const* d_in, const int* in_sizes, int n_in,
                              void* d_out, int out_size, void* d_ws, size_t ws_size,
                              hipStream_t stream) {
  const float* x  = (const float*)d_in[0];
  const float* W1 = (const float*)d_in[1];
  const float* b1 = (const float*)d_in[2];
  const float* W2 = (const float*)d_in[3];
  const float* b2 = (const float*)d_in[4];
  const float* W3 = (const float*)d_in[5];
  const float* b3 = (const float*)d_in[6];
  float* out = (float*)d_out;

  char* p = (char*)d_ws;
  auto alloc = [&](size_t bytes) {
    char* r = p;
    p += (bytes + 255) & ~(size_t)255;
    return r;
  };
  f16* xm2  = (f16*)alloc((size_t)NB * 2 * NIN * 2);     // 80 MiB
  f16* W1T  = (f16*)alloc((size_t)NHID * 2 * NIN * 2);   // 5 MiB
  f16* W2T  = (f16*)alloc((size_t)NHID * 2 * NHID * 2);  // 16 MiB
  f16* W3T  = (f16*)alloc((size_t)NOUTP * 2 * NHID * 2); // 6 MiB
  float* fpb   = (float*)alloc((size_t)NB * 4);
  int* list0   = (int*)alloc((size_t)NB * 4);
  int* list1   = (int*)alloc((size_t)NB * 4);
  int* cnt     = (int*)alloc(32 * 4);

  size_t used = (size_t)(p - (char*)d_ws);
  size_t remain = (ws_size > used) ? (ws_size - used) : 0;
  long long chl = (long long)(remain / ((size_t)2 * 2 * NHID * 2)); // h1+h2 = 16384 B/row
  int CH = (int)(chl > NB ? NB : chl);
  CH &= ~127;
  if (CH > 8192) CH = 8192;   // grid = 1024 blocks = exactly 2 scheduling waves (512 slots)
  if (CH < 128) CH = 128;
  f16* h1 = (f16*)alloc((size_t)CH * 2 * NHID * 2);
  f16* h2 = (f16*)alloc((size_t)CH * 2 * NHID * 2);
  int nchunks = (NB + CH - 1) / CH;

  k_prepW<<<dim3(NIN / 32, NHID / 32), 256, 0, stream>>>(W1, W1T, NIN, NHID);
  k_prepW<<<dim3(NHID / 32, NHID / 32), 256, 0, stream>>>(W2, W2T, NHID, NHID);
  k_prepW<<<dim3(NHID / 32, NOUTP / 32), 256, 0, stream>>>(W3, W3T, NHID, NOUT);
  k_splitX<<<(NB * NH) / 256, 256, 0, stream>>>(x, xm2);
  k_init<<<(NB * NM) / 256, 256, 0, stream>>>(xm2, fpb, list0, cnt);

  for (int t = 0; t < ITERS; ++t) {
    const int* lc = (t & 1) ? list1 : list0;
    int* ln       = (t & 1) ? list0 : list1;
    const int* cc = cnt + t;
    int* cn       = cnt + t + 1;
    for (int c = 0; c < nchunks; ++c) {
      int off = c * CH;
      int rows = NB - off; if (rows > CH) rows = CH;
      int g1 = (CH / 128) * 16;
      k_l1<<<g1, 256, 0, stream>>>(xm2, W1T, b1, h1, lc, cc, off, rows);
      k_l2<<<g1, 256, 0, stream>>>(h1, W2T, b2, h2, cc, off, rows);
      int g3 = (CH / 128) * 6;
      k_l3<<<g3, 256, 0, stream>>>(h2, W3T, b3, xm2, fpb, lc, ln, cc, cn, off, rows);
    }
  }
  k_final<<<NB / 256, 256, 0, stream>>>(fpb, out);
}